// Round 11
// baseline (149.519 us; speedup 1.0000x reference)
//
#include <hip/hip_runtime.h>
#include <hip/hip_bf16.h>

// Problem dims
constexpr int BDIM = 16384;  // B (GEMM M)
constexpr int LDIM = 4096;   // L (GEMM N)
constexpr int HDIM = 1024;   // H (GEMM K)

// GEMM tile: 128x128 (m97 shape), BK=64 (i8), 256 threads = 4 waves (2Mx2N),
// wave tile 64x64. Simple 2-phase dbuf loop, VM0+BAR per K-step.
// 32 KiB LDS + <=128 VGPR -> 4 independent blocks/CU (cross-block overlap
// absorbs the barrier drain -- m114/m97 mechanism).
constexpr int BM = 128;
constexpr int BN = 128;
constexpr int BK = 64;
constexpr int KTILES = HDIM / BK;  // 16

typedef __attribute__((ext_vector_type(4))) int i32x4;

// ---------- prep: per-row i8 quant of A and W; bias[j] = W[j].E[j] + b[j] ----------
__global__ void prep_kernel(const float* __restrict__ A, const float* __restrict__ W,
                            const float* __restrict__ E, const float* __restrict__ b,
                            signed char* __restrict__ Aq, signed char* __restrict__ Wq,
                            float* __restrict__ sA, float* __restrict__ sW,
                            float* __restrict__ bias) {
  const int bid = blockIdx.x;
  const int w = threadIdx.x >> 6;
  const int l = threadIdx.x & 63;
  const bool isW = bid < (LDIM / 4);
  const int row = isW ? bid * 4 + w : (bid - LDIM / 4) * 4 + w;
  const float4* s4 = (const float4*)((isW ? W : A) + (size_t)row * HDIM);

  float4 v[4];
  float amax = 0.f, dot = 0.f;
#pragma unroll
  for (int i = 0; i < 4; ++i) {
    v[i] = s4[i * 64 + l];
    amax = fmaxf(amax, fmaxf(fmaxf(fabsf(v[i].x), fabsf(v[i].y)),
                             fmaxf(fabsf(v[i].z), fabsf(v[i].w))));
  }
  if (isW) {
    const float4* e4 = (const float4*)(E + (size_t)row * HDIM);
#pragma unroll
    for (int i = 0; i < 4; ++i) {
      float4 ev = e4[i * 64 + l];
      dot += v[i].x * ev.x + v[i].y * ev.y + v[i].z * ev.z + v[i].w * ev.w;
    }
  }
#pragma unroll
  for (int o = 32; o > 0; o >>= 1) amax = fmaxf(amax, __shfl_xor(amax, o, 64));
  if (isW) {
#pragma unroll
    for (int o = 32; o > 0; o >>= 1) dot += __shfl_xor(dot, o, 64);
  }
  const float inv = amax > 0.f ? 127.f / amax : 0.f;
  unsigned int* dst = (unsigned int*)((isW ? Wq : Aq) + (size_t)row * HDIM);
#pragma unroll
  for (int i = 0; i < 4; ++i) {
    int q0 = (int)rintf(v[i].x * inv), q1 = (int)rintf(v[i].y * inv);
    int q2 = (int)rintf(v[i].z * inv), q3 = (int)rintf(v[i].w * inv);
    dst[i * 64 + l] =
        (q0 & 255) | ((q1 & 255) << 8) | ((q2 & 255) << 16) | ((q3 & 255) << 24);
  }
  if (l == 0) {
    if (isW) { sW[row] = amax * (1.f / 127.f); bias[row] = dot + b[row]; }
    else sA[row] = amax * (1.f / 127.f);
  }
}

// ---------- GEMM: C[B,L] = sA*sW*(Aq[B,H] . Wq[L,H]^T) + bias[L] ----------
__device__ __forceinline__ void gld_lds16(const void* g, void* l) {
  __builtin_amdgcn_global_load_lds(
      (const __attribute__((address_space(1))) void*)g,
      (__attribute__((address_space(3))) void*)l, 16, 0, 0);
}

#define MEMPIN asm volatile("" ::: "memory")
#define SCHED0 __builtin_amdgcn_sched_barrier(0)
#define BAR __builtin_amdgcn_s_barrier()
#define LGKM0 asm volatile("s_waitcnt lgkmcnt(0)" ::: "memory")
#define VM0 asm volatile("s_waitcnt vmcnt(0)" ::: "memory")

__global__ __launch_bounds__(256, 4) void gemm_kernel(
    const signed char* __restrict__ Aq,  // [BDIM, HDIM] i8
    const signed char* __restrict__ Wq,  // [LDIM, HDIM] i8
    const float* __restrict__ sA,        // [BDIM]
    const float* __restrict__ sW,        // [LDIM]
    const float* __restrict__ bias,      // [LDIM]
    float* __restrict__ C)               // [BDIM, LDIM]
{
  // dbuf: 2 x (A 8KB + B 8KB) = 32 KiB -> 4 blocks/CU.
  __shared__ __attribute__((aligned(128))) signed char As[2 * BM * BK];
  __shared__ __attribute__((aligned(128))) signed char Bs[2 * BN * BK];

  const int tid = threadIdx.x;
  const int w = tid >> 6;      // wave 0..3
  const int l = tid & 63;
  const int wr = w >> 1;       // 0..1 : M half (64 rows)
  const int wc = w & 1;        // 0..1 : N half (64 cols)
  const int lr = l & 15;
  const int hi = l >> 4;

  // Swizzle (4096 blocks): xcd = bid&7 owns 16 mblks (A set 2MB, L2-resident);
  // mblk inner, nblk outer -> all XCDs stream the same 128KB B strip
  // simultaneously (L3 temporal locality). Bijective: 8*16*32 = 4096.
  const int bid = blockIdx.x;
  const int idx = bid >> 3;               // 0..511
  const int mblk = (bid & 7) * 16 + (idx & 15);  // 0..127
  const int nblk = idx >> 4;                     // 0..31
  const int brow = mblk * BM;
  const int bcol = nblk * BN;

  // staging: one gld_lds16 = 256thr x 16B = 4 KiB = 64 rows x 64B.
  // thread t: row=t>>2, chunk=(t&3)^((row>>1)&3) pre-swizzled (involution).
  const int srow = tid >> 2;                      // 0..63
  const int scn = (tid & 3) ^ ((tid >> 3) & 3);
  const signed char* aSrc = Aq + (size_t)(brow + srow) * HDIM + scn * 16;
  const signed char* bSrc = Wq + (size_t)(bcol + srow) * HDIM + scn * 16;

  // fragment-read byte offset within a 64B row (same XOR on read side)
  const int c0 = (hi ^ ((lr >> 1) & 3)) * 16;
  const int rowA = wr * 64 + lr;
  const int rowB = wc * 64 + lr;

  i32x4 acc[4][4] = {};
  i32x4 aF[4], bF[4];

  // stage full K-tile kk into buf d: A 2 instrs (rows 0-63, 64-127), B same.
#define STAGE(d, kk)                                                           \
  { const signed char* a_ = aSrc + (kk) * BK;                                  \
    gld_lds16(a_, &As[(d) * 8192 + w * 1024]);                                 \
    gld_lds16(a_ + (size_t)64 * HDIM, &As[(d) * 8192 + 4096 + w * 1024]);      \
    const signed char* b_ = bSrc + (kk) * BK;                                  \
    gld_lds16(b_, &Bs[(d) * 8192 + w * 1024]);                                 \
    gld_lds16(b_ + (size_t)64 * HDIM, &Bs[(d) * 8192 + 4096 + w * 1024]); }

#define READ_AB(d)                                                             \
  _Pragma("unroll") for (int mi = 0; mi < 4; ++mi)                             \
    aF[mi] = *(const i32x4*)&As[(d) * 8192 + (rowA + mi * 16) * 64 + c0];      \
  _Pragma("unroll") for (int ni = 0; ni < 4; ++ni)                             \
    bF[ni] = *(const i32x4*)&Bs[(d) * 8192 + (rowB + ni * 16) * 64 + c0];

#define MFMA16                                                                 \
  _Pragma("unroll") for (int mi = 0; mi < 4; ++mi) {                           \
    _Pragma("unroll") for (int ni = 0; ni < 4; ++ni) {                         \
      acc[mi][ni] = __builtin_amdgcn_mfma_i32_16x16x64_i8(                     \
          aF[mi], bF[ni], acc[mi][ni], 0, 0, 0);                               \
    }                                                                          \
  }

  // region t (buf d=t&1): issue STAGE(t+1)->d^1 FIRST (T3 recipe), ds_read
  // this tile, MFMA, then VM0+BAR (next tile ready). Cross-block overlap
  // (4 blocks/CU, desynced) hides the drain.
#define REGION(d, SS, kk1, TAIL)                                               \
  { if (SS) STAGE((d) ^ 1, (kk1));                                             \
    READ_AB(d)                                                                 \
    SCHED0; LGKM0; SCHED0;                                                     \
    MFMA16                                                                     \
    SCHED0;                                                                    \
    if (!(TAIL)) { VM0; MEMPIN; BAR; MEMPIN; } }

  // prologue: tile 0 -> buf 0
  STAGE(0, 0);
  VM0;
  MEMPIN; BAR;

#pragma unroll 1
  for (int t = 0; t < KTILES - 2; t += 2) {
    REGION(0, 1, t + 1, 0);
    REGION(1, 1, t + 2, 0);
  }
  REGION(0, 1, KTILES - 1, 0);
  REGION(1, 0, 0, 1);

  // epilogue: dequant out = sA[r]*sW[c]*acc + bias[c]
  float sw4[4], bv[4];
#pragma unroll
  for (int ni = 0; ni < 4; ++ni) {
    const int cc = bcol + wc * 64 + ni * 16 + lr;
    sw4[ni] = sW[cc];
    bv[ni] = bias[cc];
  }
  const int orow0 = brow + wr * 64 + hi * 4;
  const int ocol0 = bcol + wc * 64 + lr;
#pragma unroll
  for (int mi = 0; mi < 4; ++mi) {
#pragma unroll
    for (int r = 0; r < 4; ++r) {
      const float sa = sA[orow0 + mi * 16 + r];
#pragma unroll
      for (int ni = 0; ni < 4; ++ni) {
        C[(size_t)(orow0 + mi * 16 + r) * LDIM + ocol0 + ni * 16] =
            (float)acc[mi][ni][r] * (sa * sw4[ni]) + bv[ni];
      }
    }
  }
#undef REGION
#undef MFMA16
#undef READ_AB
#undef STAGE
}

extern "C" void kernel_launch(void* const* d_in, const int* in_sizes, int n_in,
                              void* d_out, int out_size, void* d_ws, size_t ws_size,
                              hipStream_t stream) {
  const float* bert = (const float*)d_in[0];  // [B,H]
  const float* emb  = (const float*)d_in[1];  // [L,H]
  const float* W    = (const float*)d_in[2];  // [L,H]
  const float* b    = (const float*)d_in[3];  // [L]
  float* out = (float*)d_out;

  // ws layout: Aq 16MB | Wq 4MB | sA 64KB | sW 16KB | bias 16KB
  char* ws = (char*)d_ws;
  signed char* Aq = (signed char*)ws;
  signed char* Wq = (signed char*)(ws + (size_t)BDIM * HDIM);
  float* sAp  = (float*)(ws + (size_t)BDIM * HDIM + (size_t)LDIM * HDIM);
  float* sWp  = (float*)((char*)sAp + BDIM * sizeof(float));
  float* bias = (float*)((char*)sWp + LDIM * sizeof(float));

  hipLaunchKernelGGL(prep_kernel, dim3(LDIM / 4 + BDIM / 4), dim3(256), 0, stream,
                     bert, W, emb, b, Aq, Wq, sAp, sWp, bias);
  hipLaunchKernelGGL(gemm_kernel, dim3((BDIM / BM) * (LDIM / BN)), dim3(256), 0, stream,
                     Aq, Wq, sAp, sWp, bias, out);
}

// Round 12
// 134.137 us; speedup vs baseline: 1.1147x; 1.1147x over previous
//
#include <hip/hip_runtime.h>
#include <hip/hip_bf16.h>

// Problem dims
constexpr int BDIM = 16384;  // B (GEMM M)
constexpr int LDIM = 4096;   // L (GEMM N)
constexpr int HDIM = 1024;   // H (GEMM K)

// GEMM tile: 256x128, BK=64 (i8), 256 threads = 4 waves (2Mx2N),
// wave tile 128x64 (85 i8-ops/LDS-byte > 75 break-even).
// A,B in 3-slot LDS rings, stage distance 2, counted vmcnt(6),
// ONE barrier per K-tile. 72 KiB LDS, ~205 VGPR -> 2 blocks/CU.
constexpr int BM = 256;
constexpr int BN = 128;
constexpr int BK = 64;
constexpr int KTILES = HDIM / BK;  // 16

typedef __attribute__((ext_vector_type(4))) int i32x4;

// ---------- prep: per-row i8 quant of A and W; bias[j] = W[j].E[j] + b[j] ----------
__global__ void prep_kernel(const float* __restrict__ A, const float* __restrict__ W,
                            const float* __restrict__ E, const float* __restrict__ b,
                            signed char* __restrict__ Aq, signed char* __restrict__ Wq,
                            float* __restrict__ sA, float* __restrict__ sW,
                            float* __restrict__ bias) {
  const int bid = blockIdx.x;
  const int w = threadIdx.x >> 6;
  const int l = threadIdx.x & 63;
  const bool isW = bid < (LDIM / 4);
  const int row = isW ? bid * 4 + w : (bid - LDIM / 4) * 4 + w;
  const float4* s4 = (const float4*)((isW ? W : A) + (size_t)row * HDIM);

  float4 v[4];
  float amax = 0.f, dot = 0.f;
#pragma unroll
  for (int i = 0; i < 4; ++i) {
    v[i] = s4[i * 64 + l];
    amax = fmaxf(amax, fmaxf(fmaxf(fabsf(v[i].x), fabsf(v[i].y)),
                             fmaxf(fabsf(v[i].z), fabsf(v[i].w))));
  }
  if (isW) {
    const float4* e4 = (const float4*)(E + (size_t)row * HDIM);
#pragma unroll
    for (int i = 0; i < 4; ++i) {
      float4 ev = e4[i * 64 + l];
      dot += v[i].x * ev.x + v[i].y * ev.y + v[i].z * ev.z + v[i].w * ev.w;
    }
  }
#pragma unroll
  for (int o = 32; o > 0; o >>= 1) amax = fmaxf(amax, __shfl_xor(amax, o, 64));
  if (isW) {
#pragma unroll
    for (int o = 32; o > 0; o >>= 1) dot += __shfl_xor(dot, o, 64);
  }
  const float inv = amax > 0.f ? 127.f / amax : 0.f;
  unsigned int* dst = (unsigned int*)((isW ? Wq : Aq) + (size_t)row * HDIM);
#pragma unroll
  for (int i = 0; i < 4; ++i) {
    int q0 = (int)rintf(v[i].x * inv), q1 = (int)rintf(v[i].y * inv);
    int q2 = (int)rintf(v[i].z * inv), q3 = (int)rintf(v[i].w * inv);
    dst[i * 64 + l] =
        (q0 & 255) | ((q1 & 255) << 8) | ((q2 & 255) << 16) | ((q3 & 255) << 24);
  }
  if (l == 0) {
    if (isW) { sW[row] = amax * (1.f / 127.f); bias[row] = dot + b[row]; }
    else sA[row] = amax * (1.f / 127.f);
  }
}

// ---------- GEMM: C[B,L] = sA*sW*(Aq[B,H] . Wq[L,H]^T) + bias[L] ----------
__device__ __forceinline__ void gld_lds16(const void* g, void* l) {
  __builtin_amdgcn_global_load_lds(
      (const __attribute__((address_space(1))) void*)g,
      (__attribute__((address_space(3))) void*)l, 16, 0, 0);
}

#define MEMPIN asm volatile("" ::: "memory")
#define SCHED0 __builtin_amdgcn_sched_barrier(0)
#define BAR __builtin_amdgcn_s_barrier()
#define LGKM0 asm volatile("s_waitcnt lgkmcnt(0)" ::: "memory")
#define VM6 asm volatile("s_waitcnt vmcnt(6)" ::: "memory")
#define VM0 asm volatile("s_waitcnt vmcnt(0)" ::: "memory")
#define VMNONE (void)0

__global__ __launch_bounds__(256, 2) void gemm_kernel(
    const signed char* __restrict__ Aq,  // [BDIM, HDIM] i8
    const signed char* __restrict__ Wq,  // [LDIM, HDIM] i8
    const float* __restrict__ sA,        // [BDIM]
    const float* __restrict__ sW,        // [LDIM]
    const float* __restrict__ bias,      // [LDIM]
    float* __restrict__ C)               // [BDIM, LDIM]
{
  // As: 3 x 16KB ring. Bs: 3 x 8KB ring. 72 KiB -> 2 blocks/CU.
  __shared__ __attribute__((aligned(128))) signed char As[3 * BM * BK];
  __shared__ __attribute__((aligned(128))) signed char Bs[3 * BN * BK];

  const int tid = threadIdx.x;
  const int w = tid >> 6;      // wave 0..3
  const int l = tid & 63;
  const int wr = w >> 1;       // 0..1 : M half (128 rows)
  const int wc = w & 1;        // 0..1 : N half (64 cols)
  const int lr = l & 15;
  const int hi = l >> 4;

  // XCD-aware swizzle (2048 blocks, %8==0 -> bijective), nblk inner.
  const int bid = blockIdx.x;
  const int swz = (bid & 7) * 256 + (bid >> 3);
  const int mblk = swz >> 5;   // 64
  const int nblk = swz & 31;   // 32
  const int brow = mblk * BM;
  const int bcol = nblk * BN;

  // staging: one gld_lds16 = 256thr x 16B = 4 KiB = 64 rows x 64B.
  // thread t: row=t>>2, chunk=(t&3)^((row>>1)&3) pre-swizzled (involution).
  const int srow = tid >> 2;                      // 0..63
  const int scn = (tid & 3) ^ ((tid >> 3) & 3);
  const signed char* aSrc = Aq + (size_t)(brow + srow) * HDIM + scn * 16;
  const signed char* bSrc = Wq + (size_t)(bcol + srow) * HDIM + scn * 16;

  // fragment-read byte offset within a 64B row (same XOR on read side)
  const int c0 = (hi ^ ((lr >> 1) & 3)) * 16;

  i32x4 acc[8][4] = {};
  i32x4 aF[8], bF[4];

  // A tile = 256 rows: 4 issues of 64 rows. B tile = 128 rows: 2 issues.
#define ISSUE_A(s, kk)                                                         \
  { const signed char* s_ = aSrc + (kk) * BK;                                  \
    _Pragma("unroll") for (int i = 0; i < 4; ++i)                              \
      gld_lds16(s_ + (size_t)64 * i * HDIM,                                    \
                &As[(s) * 16384 + i * 4096 + w * 1024]); }
#define ISSUE_B(s, kk)                                                         \
  { const signed char* s_ = bSrc + (kk) * BK;                                  \
    _Pragma("unroll") for (int i = 0; i < 2; ++i)                              \
      gld_lds16(s_ + (size_t)64 * i * HDIM,                                    \
                &Bs[(s) * 8192 + i * 4096 + w * 1024]); }

#define READ_AB(s)                                                             \
  _Pragma("unroll") for (int mi = 0; mi < 8; ++mi)                             \
    aF[mi] = *(const i32x4*)&As[(s) * 16384 +                                  \
                                (wr * 128 + mi * 16 + lr) * 64 + c0];          \
  _Pragma("unroll") for (int ni = 0; ni < 4; ++ni)                             \
    bF[ni] = *(const i32x4*)&Bs[(s) * 8192 +                                   \
                                (wc * 64 + ni * 16 + lr) * 64 + c0];

#define MFMA32                                                                 \
  _Pragma("unroll") for (int mi = 0; mi < 8; ++mi) {                           \
    _Pragma("unroll") for (int ni = 0; ni < 4; ++ni) {                         \
      acc[mi][ni] = __builtin_amdgcn_mfma_i32_16x16x64_i8(                     \
          aF[mi], bF[ni], acc[mi][ni], 0, 0, 0);                               \
    }                                                                          \
  }

  // region t (read slot s=t%3): issue tile t+2 -> slot (t+2)%3 (6 loads,
  // 2 regions of latency slack); ds_read; lgkm0; 32 MFMA; vmcnt(6) ensures
  // tile t+1 landed (its 6 loads issued a region ago; 6 youngest = t+2
  // stay in flight); ONE barrier. Slots t%3,(t+1)%3 read vs (t+2)%3
  // written -- disjoint mod 3; drift bounded by the single barrier.
#define REGION(s, s2, SS, kk2, VMW, DOBAR)                                     \
  { READ_AB(s)                                                                 \
    if (SS) { ISSUE_A((s2), (kk2)); ISSUE_B((s2), (kk2)); }                    \
    SCHED0; LGKM0; SCHED0;                                                     \
    __builtin_amdgcn_s_setprio(1);                                             \
    MFMA32                                                                     \
    __builtin_amdgcn_s_setprio(0);                                             \
    SCHED0;                                                                    \
    VMW; MEMPIN;                                                               \
    if (DOBAR) BAR;                                                            \
    MEMPIN; }

  // prologue: tiles 0,1 -> slots 0,1 (6+6 loads); vm6 -> tile 0 landed.
  ISSUE_A(0, 0); ISSUE_B(0, 0);
  ISSUE_A(1, 1); ISSUE_B(1, 1);
  VM6;
  MEMPIN; BAR;

  // regions 0..11 (period 3), staging tiles 2..13
#pragma unroll 1
  for (int t = 0; t < 12; t += 3) {
    REGION(0, 2, 1, t + 2, VM6, 1);
    REGION(1, 0, 1, t + 3, VM6, 1);
    REGION(2, 1, 1, t + 4, VM6, 1);
  }
  // regions 12..15: stage tiles 14,15 then drain
  REGION(0, 2, 1, 14, VM6, 1);
  REGION(1, 0, 1, 15, VM6, 1);
  REGION(2, 0, 0, 0, VM0, 1);
  REGION(0, 0, 0, 0, VMNONE, 0);

  // epilogue: dequant out = sA[r]*sW[c]*acc + bias[c]
  float sw4[4], bv[4];
#pragma unroll
  for (int ni = 0; ni < 4; ++ni) {
    const int cc = bcol + wc * 64 + ni * 16 + lr;
    sw4[ni] = sW[cc];
    bv[ni] = bias[cc];
  }
  const int orow0 = brow + wr * 128 + hi * 4;
  const int ocol0 = bcol + wc * 64 + lr;
#pragma unroll
  for (int mi = 0; mi < 8; ++mi) {
#pragma unroll
    for (int r = 0; r < 4; ++r) {
      const float sa = sA[orow0 + mi * 16 + r];
#pragma unroll
      for (int ni = 0; ni < 4; ++ni) {
        C[(size_t)(orow0 + mi * 16 + r) * LDIM + ocol0 + ni * 16] =
            (float)acc[mi][ni][r] * (sa * sw4[ni]) + bv[ni];
      }
    }
  }
#undef REGION
#undef MFMA32
#undef READ_AB
#undef ISSUE_A
#undef ISSUE_B
}

extern "C" void kernel_launch(void* const* d_in, const int* in_sizes, int n_in,
                              void* d_out, int out_size, void* d_ws, size_t ws_size,
                              hipStream_t stream) {
  const float* bert = (const float*)d_in[0];  // [B,H]
  const float* emb  = (const float*)d_in[1];  // [L,H]
  const float* W    = (const float*)d_in[2];  // [L,H]
  const float* b    = (const float*)d_in[3];  // [L]
  float* out = (float*)d_out;

  // ws layout: Aq 16MB | Wq 4MB | sA 64KB | sW 16KB | bias 16KB
  char* ws = (char*)d_ws;
  signed char* Aq = (signed char*)ws;
  signed char* Wq = (signed char*)(ws + (size_t)BDIM * HDIM);
  float* sAp  = (float*)(ws + (size_t)BDIM * HDIM + (size_t)LDIM * HDIM);
  float* sWp  = (float*)((char*)sAp + BDIM * sizeof(float));
  float* bias = (float*)((char*)sWp + LDIM * sizeof(float));

  hipLaunchKernelGGL(prep_kernel, dim3(LDIM / 4 + BDIM / 4), dim3(256), 0, stream,
                     bert, W, emb, b, Aq, Wq, sAp, sWp, bias);
  hipLaunchKernelGGL(gemm_kernel, dim3((BDIM / BM) * (LDIM / BN)), dim3(256), 0, stream,
                     Aq, Wq, sAp, sWp, bias, out);
}

// Round 13
// 128.332 us; speedup vs baseline: 1.1651x; 1.0452x over previous
//
#include <hip/hip_runtime.h>
#include <hip/hip_bf16.h>

// Problem dims
constexpr int BDIM = 16384;  // B (GEMM M)
constexpr int LDIM = 4096;   // L (GEMM N)
constexpr int HDIM = 1024;   // H (GEMM K)

// GEMM tile: 256x128, BK=64 (i8), 256 threads = 4 waves (2Mx2N),
// wave tile 128x64. A,B in 3-slot LDS rings, distance-2 staging, vmcnt(6),
// ONE barrier per K-tile (R12 loop, byte-identical LDS contents).
// NEW: Aq/Wq stored PANEL-MAJOR TILED ([panel][ktile][row][64B], 16B-subchunk
// XOR swizzle pre-applied by prep) -> each staging instruction reads ONE
// contiguous 4KB block (vs 64 scattered 64B segments).
constexpr int BM = 256;
constexpr int BN = 128;
constexpr int BK = 64;
constexpr int KTILES = HDIM / BK;  // 16

typedef __attribute__((ext_vector_type(4))) int i32x4;

// ---------- prep: per-row i8 quant (tiled+swizzled layout); bias ----------
__global__ void prep_kernel(const float* __restrict__ A, const float* __restrict__ W,
                            const float* __restrict__ E, const float* __restrict__ b,
                            signed char* __restrict__ Aq, signed char* __restrict__ Wq,
                            float* __restrict__ sA, float* __restrict__ sW,
                            float* __restrict__ bias) {
  const int bid = blockIdx.x;
  const int w = threadIdx.x >> 6;
  const int l = threadIdx.x & 63;
  const bool isW = bid < (LDIM / 4);
  const int row = isW ? bid * 4 + w : (bid - LDIM / 4) * 4 + w;
  const float4* s4 = (const float4*)((isW ? W : A) + (size_t)row * HDIM);

  float4 v[4];
  float amax = 0.f, dot = 0.f;
#pragma unroll
  for (int i = 0; i < 4; ++i) {
    v[i] = s4[i * 64 + l];
    amax = fmaxf(amax, fmaxf(fmaxf(fabsf(v[i].x), fabsf(v[i].y)),
                             fmaxf(fabsf(v[i].z), fabsf(v[i].w))));
  }
  if (isW) {
    const float4* e4 = (const float4*)(E + (size_t)row * HDIM);
#pragma unroll
    for (int i = 0; i < 4; ++i) {
      float4 ev = e4[i * 64 + l];
      dot += v[i].x * ev.x + v[i].y * ev.y + v[i].z * ev.z + v[i].w * ev.w;
    }
  }
#pragma unroll
  for (int o = 32; o > 0; o >>= 1) amax = fmaxf(amax, __shfl_xor(amax, o, 64));
  if (isW) {
#pragma unroll
    for (int o = 32; o > 0; o >>= 1) dot += __shfl_xor(dot, o, 64);
  }
  const float inv = amax > 0.f ? 127.f / amax : 0.f;

  // tiled + pre-swizzled store:
  //   panel P (PS rows), row-in-panel rin, tile t (64B), dword dw (0..15),
  //   16B-subchunk sub stored at slot (sub ^ ((rin>>1)&3)).
  const int PS = isW ? BN : BM;
  const int P = isW ? (row >> 7) : (row >> 8);
  const int rin = row & (PS - 1);
  const int key = (rin >> 1) & 3;
  unsigned int* dstb = (unsigned int*)(isW ? Wq : Aq);
  const size_t pbase = (size_t)P * 16 * PS * 16;  // dwords per panel
#pragma unroll
  for (int i = 0; i < 4; ++i) {
    int q0 = (int)rintf(v[i].x * inv), q1 = (int)rintf(v[i].y * inv);
    int q2 = (int)rintf(v[i].z * inv), q3 = (int)rintf(v[i].w * inv);
    unsigned int packed =
        (q0 & 255) | ((q1 & 255) << 8) | ((q2 & 255) << 16) | ((q3 & 255) << 24);
    const int d = i * 64 + l;          // original dword index in row (0..255)
    const int t = d >> 4;              // k-tile 0..15
    const int dw = d & 15;             // dword within 64B slice
    const int sub = ((dw >> 2) ^ key); // swizzled 16B slot
    dstb[pbase + ((size_t)t * PS + rin) * 16 + sub * 4 + (dw & 3)] = packed;
  }
  if (l == 0) {
    if (isW) { sW[row] = amax * (1.f / 127.f); bias[row] = dot + b[row]; }
    else sA[row] = amax * (1.f / 127.f);
  }
}

// ---------- GEMM: C[B,L] = sA*sW*(Aq . Wq^T) + bias[L] ----------
__device__ __forceinline__ void gld_lds16(const void* g, void* l) {
  __builtin_amdgcn_global_load_lds(
      (const __attribute__((address_space(1))) void*)g,
      (__attribute__((address_space(3))) void*)l, 16, 0, 0);
}

#define MEMPIN asm volatile("" ::: "memory")
#define SCHED0 __builtin_amdgcn_sched_barrier(0)
#define BAR __builtin_amdgcn_s_barrier()
#define LGKM0 asm volatile("s_waitcnt lgkmcnt(0)" ::: "memory")
#define VM6 asm volatile("s_waitcnt vmcnt(6)" ::: "memory")
#define VM0 asm volatile("s_waitcnt vmcnt(0)" ::: "memory")
#define VMNONE (void)0

__global__ __launch_bounds__(256, 2) void gemm_kernel(
    const signed char* __restrict__ Aq,  // tiled [64][16][256][64]
    const signed char* __restrict__ Wq,  // tiled [32][16][128][64]
    const float* __restrict__ sA,        // [BDIM]
    const float* __restrict__ sW,        // [LDIM]
    const float* __restrict__ bias,      // [LDIM]
    float* __restrict__ C)               // [BDIM, LDIM]
{
  // As: 3 x 16KB ring. Bs: 3 x 8KB ring. 72 KiB -> 2 blocks/CU.
  __shared__ __attribute__((aligned(128))) signed char As[3 * BM * BK];
  __shared__ __attribute__((aligned(128))) signed char Bs[3 * BN * BK];

  const int tid = threadIdx.x;
  const int w = tid >> 6;      // wave 0..3
  const int l = tid & 63;
  const int wr = w >> 1;       // 0..1 : M half (128 rows)
  const int wc = w & 1;        // 0..1 : N half (64 cols)
  const int lr = l & 15;
  const int hi = l >> 4;

  // XCD-aware swizzle (2048 blocks, %8==0 -> bijective), nblk inner.
  const int bid = blockIdx.x;
  const int swz = (bid & 7) * 256 + (bid >> 3);
  const int mblk = swz >> 5;   // 64
  const int nblk = swz & 31;   // 32
  const int brow = mblk * BM;
  const int bcol = nblk * BN;

  // staging sources: dense panel files; each instruction reads 4KB contiguous.
  const signed char* aFile = Aq + (size_t)mblk * (16 * BM * 64) + tid * 16;
  const signed char* bFile = Wq + (size_t)nblk * (16 * BN * 64) + tid * 16;

  // fragment-read byte offset within a 64B row (XOR read side; data in LDS
  // is byte-identical to the R12 layout)
  const int c0 = (hi ^ ((lr >> 1) & 3)) * 16;

  i32x4 acc[8][4] = {};
  i32x4 aF[8], bF[4];

  // A k-tile = 16KB dense: 4 instrs of 4KB. B k-tile = 8KB: 2 instrs.
#define ISSUE_A(s, kk)                                                         \
  { const signed char* s_ = aFile + (size_t)(kk) * (BM * 64);                  \
    _Pragma("unroll") for (int i = 0; i < 4; ++i)                              \
      gld_lds16(s_ + i * 4096, &As[(s) * 16384 + i * 4096 + w * 1024]); }
#define ISSUE_B(s, kk)                                                         \
  { const signed char* s_ = bFile + (size_t)(kk) * (BN * 64);                  \
    _Pragma("unroll") for (int i = 0; i < 2; ++i)                              \
      gld_lds16(s_ + i * 4096, &Bs[(s) * 8192 + i * 4096 + w * 1024]); }

#define READ_AB(s)                                                             \
  _Pragma("unroll") for (int mi = 0; mi < 8; ++mi)                             \
    aF[mi] = *(const i32x4*)&As[(s) * 16384 +                                  \
                                (wr * 128 + mi * 16 + lr) * 64 + c0];          \
  _Pragma("unroll") for (int ni = 0; ni < 4; ++ni)                             \
    bF[ni] = *(const i32x4*)&Bs[(s) * 8192 +                                   \
                                (wc * 64 + ni * 16 + lr) * 64 + c0];

#define MFMA32                                                                 \
  _Pragma("unroll") for (int mi = 0; mi < 8; ++mi) {                           \
    _Pragma("unroll") for (int ni = 0; ni < 4; ++ni) {                         \
      acc[mi][ni] = __builtin_amdgcn_mfma_i32_16x16x64_i8(                     \
          aF[mi], bF[ni], acc[mi][ni], 0, 0, 0);                               \
    }                                                                          \
  }

  // region t (read slot s=t%3): issue tile t+2 -> slot (t+2)%3 (6 loads, 2
  // regions of slack); ds_read; lgkm0; 32 MFMA; vmcnt(6) (tile t+1 landed);
  // ONE barrier. Slots disjoint mod 3; drift bounded by the barrier.
#define REGION(s, s2, SS, kk2, VMW, DOBAR)                                     \
  { READ_AB(s)                                                                 \
    if (SS) { ISSUE_A((s2), (kk2)); ISSUE_B((s2), (kk2)); }                    \
    SCHED0; LGKM0; SCHED0;                                                     \
    __builtin_amdgcn_s_setprio(1);                                             \
    MFMA32                                                                     \
    __builtin_amdgcn_s_setprio(0);                                             \
    SCHED0;                                                                    \
    VMW; MEMPIN;                                                               \
    if (DOBAR) BAR;                                                            \
    MEMPIN; }

  // prologue: tiles 0,1 -> slots 0,1; vm6 -> tile 0 landed.
  ISSUE_A(0, 0); ISSUE_B(0, 0);
  ISSUE_A(1, 1); ISSUE_B(1, 1);
  VM6;
  MEMPIN; BAR;

#pragma unroll 1
  for (int t = 0; t < 12; t += 3) {
    REGION(0, 2, 1, t + 2, VM6, 1);
    REGION(1, 0, 1, t + 3, VM6, 1);
    REGION(2, 1, 1, t + 4, VM6, 1);
  }
  REGION(0, 2, 1, 14, VM6, 1);
  REGION(1, 0, 1, 15, VM6, 1);
  REGION(2, 0, 0, 0, VM0, 1);
  REGION(0, 0, 0, 0, VMNONE, 0);

  // epilogue: dequant out = sA[r]*sW[c]*acc + bias[c]
  float sw4[4], bv[4];
#pragma unroll
  for (int ni = 0; ni < 4; ++ni) {
    const int cc = bcol + wc * 64 + ni * 16 + lr;
    sw4[ni] = sW[cc];
    bv[ni] = bias[cc];
  }
  const int orow0 = brow + wr * 128 + hi * 4;
  const int ocol0 = bcol + wc * 64 + lr;
#pragma unroll
  for (int mi = 0; mi < 8; ++mi) {
#pragma unroll
    for (int r = 0; r < 4; ++r) {
      const float sa = sA[orow0 + mi * 16 + r];
#pragma unroll
      for (int ni = 0; ni < 4; ++ni) {
        C[(size_t)(orow0 + mi * 16 + r) * LDIM + ocol0 + ni * 16] =
            (float)acc[mi][ni][r] * (sa * sw4[ni]) + bv[ni];
      }
    }
  }
#undef REGION
#undef MFMA32
#undef READ_AB
#undef ISSUE_A
#undef ISSUE_B
}

extern "C" void kernel_launch(void* const* d_in, const int* in_sizes, int n_in,
                              void* d_out, int out_size, void* d_ws, size_t ws_size,
                              hipStream_t stream) {
  const float* bert = (const float*)d_in[0];  // [B,H]
  const float* emb  = (const float*)d_in[1];  // [L,H]
  const float* W    = (const float*)d_in[2];  // [L,H]
  const float* b    = (const float*)d_in[3];  // [L]
  float* out = (float*)d_out;

  // ws layout: Aq 16MB | Wq 4MB | sA 64KB | sW 16KB | bias 16KB
  char* ws = (char*)d_ws;
  signed char* Aq = (signed char*)ws;
  signed char* Wq = (signed char*)(ws + (size_t)BDIM * HDIM);
  float* sAp  = (float*)(ws + (size_t)BDIM * HDIM + (size_t)LDIM * HDIM);
  float* sWp  = (float*)((char*)sAp + BDIM * sizeof(float));
  float* bias = (float*)((char*)sWp + LDIM * sizeof(float));

  hipLaunchKernelGGL(prep_kernel, dim3(LDIM / 4 + BDIM / 4), dim3(256), 0, stream,
                     bert, W, emb, b, Aq, Wq, sAp, sWp, bias);
  hipLaunchKernelGGL(gemm_kernel, dim3((BDIM / BM) * (LDIM / BN)), dim3(256), 0, stream,
                     Aq, Wq, sAp, sWp, bias, out);
}